// Round 1
// baseline (193.086 us; speedup 1.0000x reference)
//
#include <hip/hip_runtime.h>
#include <hip/hip_bf16.h>

// GCN fused pipeline for MI355X — fixed-capacity dst-bucket grouping,
// LDS-local E-passes, 16-way sharded pooling atomics.
// vocab=1 => h1[i] = relu(embW1*c_i + b1) piecewise-linear in scalar c_i with
// <=65 ReLU patterns (bins). g[i] = a_i*P[bin_i] + b_i*Q[bin_i].
// agg_i[d] = sum_u A_i[u]*P[u][d] + B_i[u]*Q[u][d], (A,B) per-(node,bin) LDS
// sums (2 LDS atomics/edge). Lessons: R6 - no E-scale global atomics (64B
// line write-through each); R11 - no cooperative grid.sync (8 XCDs);
// R12 - contended global atomic flush (~100 serialized RMWs/line) is a
// 71us-class floor -> shard psum/cnt and PAD per-bucket cursors to one/line.
// R13 (this round): k_group had 128 blocks on 256 CUs (17.5% occ) and passC
// 256t/33KB-LDS blocks (26.6% occ) — both latency-bound, nowhere near any
// roofline. GPB 128->512 (2 blocks/CU exact fill), passC 256->512 threads
// (4x33KB LDS + 2048 threads = exact CU fill, U-loop serial chain halved).
// Inputs: 0 x[int32 N], 1 edge_index[int32 2*E] (src then dst), 2 batch[int32 N sorted],
// 3 emb[1*64], 4 W1[64*64], 5 b1[64], 6 W2[64*64], 7 b2[64], 8 fcW[64*32], 9 fcb[32].
// Output: [G=64, 32] fp32.

#define DH 64
#define DOUT 32
#define NBIN 65
#define BW 64          // bucket width (nodes per bucket)
#define MAXNB 2048     // max buckets (N <= 131072)
#define SRCM 0x3FFFFFF // 26-bit src mask (N < 2^26)
#define CAPE 1280      // per-bucket record capacity (16B-aligned: 1280*4=5120)
#define GPB 512        // group blocks (2 blocks/CU x 256 CUs)
#define NSH 16         // pooling shards
#define CURS 16        // cursor stride in ints: one 64B line per bucket counter

// ---- group edges by dst bucket (fixed capacity) + PQ tables in extra blocks ----
__global__ __launch_bounds__(1024) void k_group(
        const int* __restrict__ src, const int* __restrict__ dst,
        int* __restrict__ cursor, unsigned* __restrict__ rec,
        const float* __restrict__ emb, const float* __restrict__ W1,
        const float* __restrict__ b1, const float* __restrict__ W2,
        float* __restrict__ tarr, float2* __restrict__ PQ, int E, int NB, int chunk) {
    __shared__ int lh[MAXNB];
    __shared__ int lb[MAXNB];
    __shared__ float ewl[DH], tl[DH], bl[DH];
    __shared__ int rl[DH], sl[DH];
    int tid = threadIdx.x, bid = blockIdx.x;
    if (bid >= GPB) {
        // ---- tables part: beta = bid-GPB in 0..64, 64 working threads ----
        int beta = bid - GPB;
        int k = tid;
        float s = 0.f, t = 0.f;
        if (k < DH) {
#pragma unroll
            for (int j = 0; j < DH; ++j) s += emb[j] * W1[j * DH + k];
            t = (s != 0.f) ? (-b1[k] / s) : INFINITY;
            ewl[k] = s; tl[k] = t; bl[k] = b1[k];
        }
        __syncthreads();
        if (k < DH) {
            int r = 0, ss = 0;
#pragma unroll
            for (int j = 0; j < DH; ++j) { r += (tl[j] <= t); ss += (tl[j] < t); }
            rl[k] = r; sl[k] = ss;
            if (beta == 0) tarr[k] = t;
        }
        __syncthreads();
        if (k < DH) {
            float p = 0.f, q = 0.f;
            for (int kk = 0; kk < DH; ++kk) {
                float e = ewl[kk];
                bool act;
                if (e > 0.f) act = (beta >= rl[kk]);
                else if (e < 0.f) act = (beta <= sl[kk]);
                else act = (bl[kk] > 0.f);
                if (act) {
                    float w = W2[kk * DH + k];
                    p += e * w;
                    q += bl[kk] * w;
                }
            }
            PQ[beta * DH + k] = make_float2(p, q);
        }
        return;
    }
    // ---- group part ----
    int c0 = bid * chunk;
    int c1 = min(c0 + chunk, E);
    for (int t = tid; t < NB; t += blockDim.x) lh[t] = 0;
    __syncthreads();
    for (int e = c0 + tid; e < c1; e += blockDim.x)
        atomicAdd(&lh[dst[e] >> 6], 1);
    __syncthreads();
    for (int t = tid; t < NB; t += blockDim.x) {
        int h = lh[t];
        lb[t] = h ? atomicAdd(&cursor[t * CURS], h) : 0;
    }
    __syncthreads();
    for (int t = tid; t < NB; t += blockDim.x) lh[t] = 0;
    __syncthreads();
    for (int e = c0 + tid; e < c1; e += blockDim.x) {
        int s = src[e], dd = dst[e];
        int bk = dd >> 6;
        int ofs = lb[bk] + atomicAdd(&lh[bk], 1);
        if (ofs < CAPE)  // 8-sigma safety clamp
            rec[bk * CAPE + ofs] = (unsigned)s | ((unsigned)(dd & 63) << 26);
    }
}

// ---- pass A: per-bucket deg count (LDS, coalesced rec stream) -> dinv ----
__global__ __launch_bounds__(256) void k_passA(const int* __restrict__ cursor,
        const unsigned* __restrict__ rec, float* __restrict__ dinv, int N) {
    __shared__ int cl[BW];
    int tid = threadIdx.x;
    if (tid < BW) cl[tid] = 0;
    __syncthreads();
    int b = blockIdx.x;
    int cnt = min(cursor[b * CURS], CAPE);
    int r0 = b * CAPE;
    for (int e = tid; e < cnt; e += blockDim.x)
        atomicAdd(&cl[rec[r0 + e] >> 26], 1);
    __syncthreads();
    if (tid < BW) {
        int i = b * BW + tid;
        if (i < N) dinv[i] = rsqrtf((float)cl[tid] + 1.0f);
    }
}

// ---- pass B: per-bucket S (uint4 rec loads, LDS atomics) -> summary4, flags ----
__global__ __launch_bounds__(256, 8) void k_passB(const int* __restrict__ cursor,
        const unsigned* __restrict__ rec, const float* __restrict__ dinv,
        const float* __restrict__ tarr, float4* __restrict__ summary,
        int* __restrict__ flags, int N) {
    __shared__ float Sl[BW];
    __shared__ float tl[DH];
    int tid = threadIdx.x;
    if (tid < BW) Sl[tid] = 0.f;
    if (tid < DH) tl[tid] = tarr[tid];
    __syncthreads();
    int b = blockIdx.x;
    int cnt = min(cursor[b * CURS], CAPE);
    int r0 = b * CAPE;
    const uint4* rq = (const uint4*)(rec + r0);  // r0*4 = b*5120, 16B aligned
    int nq = cnt >> 2;
    for (int q = tid; q < nq; q += blockDim.x) {
        uint4 r = rq[q];
        float d0 = dinv[r.x & SRCM];
        float d1 = dinv[r.y & SRCM];
        float d2 = dinv[r.z & SRCM];
        float d3 = dinv[r.w & SRCM];
        atomicAdd(&Sl[r.x >> 26], d0);
        atomicAdd(&Sl[r.y >> 26], d1);
        atomicAdd(&Sl[r.z >> 26], d2);
        atomicAdd(&Sl[r.w >> 26], d3);
    }
    int e = (nq << 2) + tid;
    if (e < cnt) {
        unsigned r = rec[r0 + e];
        atomicAdd(&Sl[r >> 26], dinv[r & SRCM]);
    }
    __syncthreads();
    if (tid < BW) {
        int i = b * BW + tid;
        if (i < N) {
            float di = dinv[i];
            float c = di * (Sl[tid] + di);
            int bb = 0;
#pragma unroll
            for (int j = 0; j < DH; ++j) bb += (tl[j] < c);
            summary[i] = make_float4(di * c, di, __uint_as_float((unsigned)bb), 0.f);
            flags[bb] = 1;  // benign race: same value
        }
    }
}

// ---- pass C: AB accumulate (uint4 rec, 2 LDS atomics/edge), compact ulist +
// readlane U-dot, self term + relu + SHARDED sorted-batch strip pooling.
// 512 threads: 8 waves x 8 nodes — halves the serial U-loop chain and fills
// the CU (4 blocks x 512 thr = 2048, 4 x 33KB LDS = 132KB). ----
__global__ __launch_bounds__(512, 8) void k_passC(const int* __restrict__ cursor,
        const unsigned* __restrict__ rec, const float4* __restrict__ summary,
        const float2* __restrict__ PQ, const int* __restrict__ flags,
        const float* __restrict__ b2, const int* __restrict__ batch,
        float* __restrict__ psum_s, float* __restrict__ cnt_s, int N, int G) {
    __shared__ __align__(16) float AB[BW * NBIN * 2];  // 33,280 B
    __shared__ unsigned char ulist[NBIN + 3];
    __shared__ int UcntS;
    int tid = threadIdx.x;  // 512
    // used-bin list via ballot (wave 0 only)
    if (tid < 64) {
        int act = (flags[tid] != 0);
        unsigned long long m = __ballot(act);
        int pos = __popcll(m & ((1ull << tid) - 1ull));
        if (act) ulist[pos] = (unsigned char)tid;
        if (tid == 0) {
            int total = __popcll(m);
            if (flags[64]) ulist[total++] = 64;
            UcntS = total;
        }
    }
    // zero AB float4-wide (8320 floats = 2080 float4)
    float4* AB4 = (float4*)AB;
    for (int t = tid; t < (BW * NBIN * 2) / 4; t += blockDim.x)
        AB4[t] = make_float4(0.f, 0.f, 0.f, 0.f);
    __syncthreads();
    int b = blockIdx.x;
    int ecnt = min(cursor[b * CURS], CAPE);
    int r0 = b * CAPE;
    const uint4* rq = (const uint4*)(rec + r0);
    int nq = ecnt >> 2;
    for (int q = tid; q < nq; q += blockDim.x) {
        uint4 r = rq[q];
        float4 s0 = summary[r.x & SRCM];
        float4 s1 = summary[r.y & SRCM];
        float4 s2 = summary[r.z & SRCM];
        float4 s3 = summary[r.w & SRCM];
        float* p0 = &AB[(((r.x >> 26)) * NBIN + __float_as_uint(s0.z)) * 2];
        atomicAdd(p0, s0.x); atomicAdd(p0 + 1, s0.y);
        float* p1 = &AB[(((r.y >> 26)) * NBIN + __float_as_uint(s1.z)) * 2];
        atomicAdd(p1, s1.x); atomicAdd(p1 + 1, s1.y);
        float* p2 = &AB[(((r.z >> 26)) * NBIN + __float_as_uint(s2.z)) * 2];
        atomicAdd(p2, s2.x); atomicAdd(p2 + 1, s2.y);
        float* p3 = &AB[(((r.w >> 26)) * NBIN + __float_as_uint(s3.z)) * 2];
        atomicAdd(p3, s3.x); atomicAdd(p3 + 1, s3.y);
    }
    int e = (nq << 2) + tid;
    if (e < ecnt) {
        unsigned r = rec[r0 + e];
        float4 sm = summary[r & SRCM];
        float* pp = &AB[((r >> 26) * NBIN + __float_as_uint(sm.z)) * 2];
        atomicAdd(pp, sm.x); atomicAdd(pp + 1, sm.y);
    }
    __syncthreads();
    int U = UcntS;
    int d = tid & 63;
    int w = tid >> 6;   // 0..7, wave w owns nodes [w*8, w*8+8)
    int n0b = w << 3;
    float2 abr[8];
#pragma unroll
    for (int j = 0; j < 8; ++j)
        abr[j] = *(const float2*)&AB[((n0b + j) * NBIN + d) * 2];
    float accv[8];
#pragma unroll
    for (int j = 0; j < 8; ++j) accv[j] = 0.f;
    for (int uu = 0; uu < U; ++uu) {
        int u = ulist[uu];  // wave-uniform
        float2 pq = PQ[u * DH + d];
        if (u < 64) {
#pragma unroll
            for (int j = 0; j < 8; ++j) {
                float ax = __int_as_float(__builtin_amdgcn_readlane(__float_as_int(abr[j].x), u));
                float ay = __int_as_float(__builtin_amdgcn_readlane(__float_as_int(abr[j].y), u));
                accv[j] += ax * pq.x + ay * pq.y;
            }
        } else {
#pragma unroll
            for (int j = 0; j < 8; ++j) {
                float2 v = *(const float2*)&AB[((n0b + j) * NBIN + 64) * 2];
                accv[j] += v.x * pq.x + v.y * pq.y;
            }
        }
    }
    // finish: self term + relu + sorted-batch strip pooling (sharded flush)
    float* psum = psum_s + (size_t)(b & (NSH - 1)) * G * DH;
    float* cnt  = cnt_s  + (size_t)(b & (NSH - 1)) * G;
    int n0 = b * BW;
    float bias = b2[d];
    float lsum = 0.f, lcnt = 0.f;
    int cb = -1;
    for (int j = 0; j < 8; ++j) {
        int i = n0 + n0b + j;
        if (i >= N) break;
        float4 sm = summary[i];
        int rb = (int)__float_as_uint(sm.z);
        float2 pq = PQ[rb * DH + d];
        float g = sm.x * pq.x + sm.y * pq.y;
        float v = fmaxf(sm.y * (accv[j] + g) + bias, 0.f);
        int bt = batch[i];
        if (bt != cb) {
            if (cb >= 0) {
                atomicAdd(&psum[cb * DH + d], lsum);
                if (d == 0) atomicAdd(&cnt[cb], lcnt);
            }
            cb = bt; lsum = 0.f; lcnt = 0.f;
        }
        lsum += v;
        if (d == 0) lcnt += 1.f;
    }
    if (cb >= 0) {
        atomicAdd(&psum[cb * DH + d], lsum);
        if (d == 0) atomicAdd(&cnt[cb], lcnt);
    }
}

// ---- out: one block per graph; reduce NSH shards, mean-pool, FC ----
__global__ __launch_bounds__(64) void k_out(const float* __restrict__ psum_s,
        const float* __restrict__ cnt_s, const float* __restrict__ fcW,
        const float* __restrict__ fcb, float* __restrict__ out, int G) {
    __shared__ float pooled[DH];
    int g = blockIdx.x, d = threadIdx.x;  // 64 threads
    float s = 0.f, cc = 0.f;
#pragma unroll
    for (int k = 0; k < NSH; ++k) {
        s += psum_s[(size_t)k * G * DH + g * DH + d];
        cc += cnt_s[(size_t)k * G + g];
    }
    pooled[d] = s / fmaxf(cc, 1.0f);
    __syncthreads();
    if (d < DOUT) {
        float o = 0.f;
#pragma unroll
        for (int kk = 0; kk < DH; ++kk) o += pooled[kk] * fcW[kk * DOUT + d];
        out[g * DOUT + d] = o + fcb[d];
    }
}

static inline size_t pad256(size_t n) { return (n + 255) & ~(size_t)255; }

extern "C" void kernel_launch(void* const* d_in, const int* in_sizes, int n_in,
                              void* d_out, int out_size, void* d_ws, size_t ws_size,
                              hipStream_t stream) {
    const int N = in_sizes[0];
    const int E = in_sizes[1] / 2;
    const int G = out_size / DOUT;
    const int NB = (N + BW - 1) / BW;

    const int* edge = (const int*)d_in[1];
    const int* src = edge;
    const int* dst = edge + E;
    const int* batch = (const int*)d_in[2];
    const float* emb = (const float*)d_in[3];
    const float* W1 = (const float*)d_in[4];
    const float* b1 = (const float*)d_in[5];
    const float* W2 = (const float*)d_in[6];
    const float* b2 = (const float*)d_in[7];
    const float* fcW = (const float*)d_in[8];
    const float* fcb = (const float*)d_in[9];
    float* out = (float*)d_out;

    // workspace. Zero region first: psum_s, cnt_s, flags, cursor (~400 KB).
    char* ws = (char*)d_ws;
    size_t off = 0;
    float* psum_s = (float*)(ws + off); off += pad256((size_t)NSH * G * DH) * 4;
    float* cnt_s  = (float*)(ws + off); off += pad256((size_t)NSH * G) * 4;
    int* flags  = (int*)(ws + off);    off += pad256(NBIN) * 4;
    int* cursor = (int*)(ws + off);    off += pad256((size_t)MAXNB * CURS) * 4;
    size_t zero_bytes = off;
    unsigned* rec = (unsigned*)(ws + off); off += pad256((size_t)MAXNB * CAPE) * 4;  // 10.5 MB
    float* dinv  = (float*)(ws + off);  off += pad256(N) * 4;
    float* tarr  = (float*)(ws + off);  off += pad256(DH) * 4;
    float2* PQ   = (float2*)(ws + off); off += pad256(NBIN * DH) * 8;
    float4* summary = (float4*)(ws + off); off += pad256(N) * 16;
    // total ~ 13.5 MB

    hipMemsetAsync(d_ws, 0, zero_bytes, stream);

    const int B = 256;
    int chunk = (E + GPB - 1) / GPB;
    k_group<<<GPB + NBIN, 1024, 0, stream>>>(src, dst, cursor, rec, emb, W1, b1, W2,
                                             tarr, PQ, E, NB, chunk);
    k_passA<<<NB, B, 0, stream>>>(cursor, rec, dinv, N);
    k_passB<<<NB, B, 0, stream>>>(cursor, rec, dinv, tarr, summary, flags, N);
    k_passC<<<NB, 512, 0, stream>>>(cursor, rec, summary, PQ, flags, b2, batch,
                                    psum_s, cnt_s, N, G);
    k_out<<<G, 64, 0, stream>>>(psum_s, cnt_s, fcW, fcb, out, G);
}

// Round 2
// 167.137 us; speedup vs baseline: 1.1553x; 1.1553x over previous
//
#include <hip/hip_runtime.h>
#include <hip/hip_bf16.h>

// GCN fused pipeline for MI355X — block-local counting sort (NO global atomics,
// NO scattered global writes), gather-compact pass, LDS-local E-passes, 8-way
// sharded pooling atomics.
// vocab=1 => h1[i] = relu(embW1*c_i + b1) piecewise-linear in scalar c_i with
// <=65 ReLU patterns (bins). g[i] = a_i*P[bin_i] + b_i*Q[bin_i].
// agg_i[d] = sum_u A_i[u]*P[u][d] + B_i[u]*Q[u][d], (A,B) per-(node,bin) LDS
// sums (2 LDS atomics/edge).
// Lessons: R6 - no E-scale global atomics (64B line write-through each);
// R11 - no cooperative grid.sync (8 XCDs); R12 - contended global atomic
// flush is a 71us-class floor -> shard psum/cnt; R13 - k_group was NOT
// latency-bound: GPB 128->512 raised occupancy 17->60% but WRITE_SIZE
// 26->60MB (800K cursor atomics x 64B write-through + finer scatter runs
// sharing lines across non-coherent XCD L2s) and dur 42->62us.
// R14 (this round): restructure the shuffle so ALL global writes are dense
// single-writer: k_group does per-block LDS counting sort into a block-private
// contiguous rec region + coalesced u16 run index; passA gathers runs
// (reads are L3-served, no write-through penalty), counts deg, and writes the
// bucket-major compacted rec2 that passB/passC stream as before. passC
// reverted to round-0 256-thread version (512-thread variant unverified,
// suspected VGPR spill at the 64-reg cap).
// Inputs: 0 x[int32 N], 1 edge_index[int32 2*E] (src then dst), 2 batch[int32 N sorted],
// 3 emb[1*64], 4 W1[64*64], 5 b1[64], 6 W2[64*64], 7 b2[64], 8 fcW[64*32], 9 fcb[32].
// Output: [G=64, 32] fp32.

#define DH 64
#define DOUT 32
#define NBIN 65
#define BW 64          // bucket width (nodes per bucket)
#define MAXNB 2048     // max buckets (N <= 131072)
#define SCAN_N 2048    // scan width (>= NB, pow2)
#define SRCM 0x3FFFFFF // 26-bit src mask (N < 2^26)
#define CAPE 1280      // per-bucket compacted capacity (16B-aligned: 1280*4=5120)
#define GPB 128        // group blocks; chunk = E/GPB ~ 12500 (fits u16 idx)
#define NSH 8          // pooling shards

// ---- group: per-block LDS counting sort -> block-private dense region + u16
// run index. Extra NBIN blocks compute PQ tables. ----
__global__ __launch_bounds__(1024) void k_group(
        const int* __restrict__ src, const int* __restrict__ dst,
        unsigned* __restrict__ rec, unsigned short* __restrict__ idx,
        const float* __restrict__ emb, const float* __restrict__ W1,
        const float* __restrict__ b1, const float* __restrict__ W2,
        float* __restrict__ tarr, float2* __restrict__ PQ, int E, int NB, int chunk) {
    __shared__ int lh[SCAN_N];
    __shared__ int lb[SCAN_N];
    __shared__ float ewl[DH], tl[DH], bl[DH];
    __shared__ int rl[DH], sl[DH];
    int tid = threadIdx.x, bid = blockIdx.x;
    if (bid >= GPB) {
        // ---- tables part: beta = bid-GPB in 0..64, 64 working threads ----
        int beta = bid - GPB;
        int k = tid;
        float s = 0.f, t = 0.f;
        if (k < DH) {
#pragma unroll
            for (int j = 0; j < DH; ++j) s += emb[j] * W1[j * DH + k];
            t = (s != 0.f) ? (-b1[k] / s) : INFINITY;
            ewl[k] = s; tl[k] = t; bl[k] = b1[k];
        }
        __syncthreads();
        if (k < DH) {
            int r = 0, ss = 0;
#pragma unroll
            for (int j = 0; j < DH; ++j) { r += (tl[j] <= t); ss += (tl[j] < t); }
            rl[k] = r; sl[k] = ss;
            if (beta == 0) tarr[k] = t;
        }
        __syncthreads();
        if (k < DH) {
            float p = 0.f, q = 0.f;
            for (int kk = 0; kk < DH; ++kk) {
                float e = ewl[kk];
                bool act;
                if (e > 0.f) act = (beta >= rl[kk]);
                else if (e < 0.f) act = (beta <= sl[kk]);
                else act = (bl[kk] > 0.f);
                if (act) {
                    float w = W2[kk * DH + k];
                    p += e * w;
                    q += bl[kk] * w;
                }
            }
            PQ[beta * DH + k] = make_float2(p, q);
        }
        return;
    }
    // ---- group part: local counting sort of chunk [c0,c1) ----
    int c0 = bid * chunk;
    int c1 = min(c0 + chunk, E);
    for (int t = tid; t < SCAN_N; t += 1024) lh[t] = 0;
    __syncthreads();
    for (int e = c0 + tid; e < c1; e += 1024)
        atomicAdd(&lh[dst[e] >> 6], 1);
    __syncthreads();
    for (int t = tid; t < SCAN_N; t += 1024) lb[t] = lh[t];
    __syncthreads();
    // inclusive scan of lb over SCAN_N (Hillis-Steele, 2 elems/thread)
    for (int ofs = 1; ofs < SCAN_N; ofs <<= 1) {
        int i1 = tid + 1024;
        int v0 = (tid >= ofs) ? lb[tid - ofs] : 0;
        int v1 = (i1 >= ofs) ? lb[i1 - ofs] : 0;
        __syncthreads();
        lb[tid] += v0; lb[i1] += v1;
        __syncthreads();
    }
    // exclusive base = incl - count; emit u16 index; keep base in lb
    size_t ib = (size_t)bid * (MAXNB + 1);
    for (int t = tid; t < NB; t += 1024) {
        int base = lb[t] - lh[t];
        idx[ib + t] = (unsigned short)base;
        lb[t] = base;
    }
    if (tid == 0) idx[ib + NB] = (unsigned short)(c1 - c0);
    __syncthreads();
    for (int t = tid; t < NB; t += 1024) lh[t] = 0;
    __syncthreads();
    // scatter into block-private dense region (writes stay within 50KB,
    // single-XCD, dense writeback; no cross-block line sharing)
    for (int e = c0 + tid; e < c1; e += 1024) {
        int s = src[e], dd = dst[e];
        int bk = dd >> 6;
        int o = lb[bk] + atomicAdd(&lh[bk], 1);
        rec[(size_t)bid * chunk + o] = (unsigned)s | ((unsigned)(dd & 63) << 26);
    }
}

// ---- pass A: per-bucket gather of GPB runs -> deg count + bucket-major
// compacted rec2 (coalesced-ish dense writes), dinv ----
__global__ __launch_bounds__(256) void k_passA(const unsigned short* __restrict__ idx,
        const unsigned* __restrict__ rec, unsigned* __restrict__ rec2,
        int* __restrict__ cnts, float* __restrict__ dinv, int N, int chunk) {
    __shared__ int rst[GPB], rln[GPB], rbs[GPB];
    __shared__ int cl[BW];
    int tid = threadIdx.x, bk = blockIdx.x;
    if (tid < BW) cl[tid] = 0;
    if (tid < GPB) {
        size_t ib = (size_t)tid * (MAXNB + 1);
        int s = idx[ib + bk];
        int e = idx[ib + bk + 1];
        rst[tid] = tid * chunk + s;
        rln[tid] = e - s;
        rbs[tid] = e - s;
    }
    __syncthreads();
    // inclusive scan of run lengths
    for (int ofs = 1; ofs < GPB; ofs <<= 1) {
        int v = 0;
        if (tid < GPB && tid >= ofs) v = rbs[tid - ofs];
        __syncthreads();
        if (tid < GPB) rbs[tid] += v;
        __syncthreads();
    }
    if (tid == 0) cnts[bk] = min(rbs[GPB - 1], CAPE);
    // gather: 2 threads per run (phase-interleaved)
    int run = tid & (GPB - 1);
    int ph = tid >> 7;  // 0/1
    int base = rbs[run] - rln[run];
    int st = rst[run], ln = rln[run];
    size_t r2 = (size_t)bk * CAPE;
    for (int j = ph; j < ln; j += 2) {
        unsigned r = rec[st + j];
        atomicAdd(&cl[r >> 26], 1);
        int o = base + j;
        if (o < CAPE) rec2[r2 + o] = r;
    }
    __syncthreads();
    if (tid < BW) {
        int i = bk * BW + tid;
        if (i < N) dinv[i] = rsqrtf((float)cl[tid] + 1.0f);
    }
}

// ---- pass B: per-bucket S (uint4 rec2 loads, LDS atomics) -> summary4, flags ----
__global__ __launch_bounds__(256, 8) void k_passB(const int* __restrict__ cnts,
        const unsigned* __restrict__ rec2, const float* __restrict__ dinv,
        const float* __restrict__ tarr, float4* __restrict__ summary,
        int* __restrict__ flags, int N) {
    __shared__ float Sl[BW];
    __shared__ float tl[DH];
    int tid = threadIdx.x;
    if (tid < BW) Sl[tid] = 0.f;
    if (tid < DH) tl[tid] = tarr[tid];
    __syncthreads();
    int b = blockIdx.x;
    int cnt = cnts[b];
    size_t r0 = (size_t)b * CAPE;
    const uint4* rq = (const uint4*)(rec2 + r0);  // r0*4 = b*5120, 16B aligned
    int nq = cnt >> 2;
    for (int q = tid; q < nq; q += blockDim.x) {
        uint4 r = rq[q];
        float d0 = dinv[r.x & SRCM];
        float d1 = dinv[r.y & SRCM];
        float d2 = dinv[r.z & SRCM];
        float d3 = dinv[r.w & SRCM];
        atomicAdd(&Sl[r.x >> 26], d0);
        atomicAdd(&Sl[r.y >> 26], d1);
        atomicAdd(&Sl[r.z >> 26], d2);
        atomicAdd(&Sl[r.w >> 26], d3);
    }
    int e = (nq << 2) + tid;
    if (e < cnt) {
        unsigned r = rec2[r0 + e];
        atomicAdd(&Sl[r >> 26], dinv[r & SRCM]);
    }
    __syncthreads();
    if (tid < BW) {
        int i = b * BW + tid;
        if (i < N) {
            float di = dinv[i];
            float c = di * (Sl[tid] + di);
            int bb = 0;
#pragma unroll
            for (int j = 0; j < DH; ++j) bb += (tl[j] < c);
            summary[i] = make_float4(di * c, di, __uint_as_float((unsigned)bb), 0.f);
            flags[bb] = 1;  // benign race: same value
        }
    }
}

// ---- pass C: AB accumulate (uint4 rec2, 2 LDS atomics/edge), compact ulist +
// readlane U-dot, self term + relu + SHARDED sorted-batch strip pooling.
// (round-0 known-good 256-thread version) ----
__global__ __launch_bounds__(256, 4) void k_passC(const int* __restrict__ cnts,
        const unsigned* __restrict__ rec2, const float4* __restrict__ summary,
        const float2* __restrict__ PQ, const int* __restrict__ flags,
        const float* __restrict__ b2, const int* __restrict__ batch,
        float* __restrict__ psum_s, float* __restrict__ cnt_s, int N, int G) {
    __shared__ __align__(16) float AB[BW * NBIN * 2];  // 33,280 B
    __shared__ unsigned char ulist[NBIN + 3];
    __shared__ int UcntS;
    int tid = threadIdx.x;  // 256
    // used-bin list via ballot
    if (tid < 64) {
        int act = (flags[tid] != 0);
        unsigned long long m = __ballot(act);
        int pos = __popcll(m & ((1ull << tid) - 1ull));
        if (act) ulist[pos] = (unsigned char)tid;
        if (tid == 0) {
            int total = __popcll(m);
            if (flags[64]) ulist[total++] = 64;
            UcntS = total;
        }
    }
    // zero AB float4-wide (8320 floats = 2080 float4)
    float4* AB4 = (float4*)AB;
    for (int t = tid; t < (BW * NBIN * 2) / 4; t += blockDim.x)
        AB4[t] = make_float4(0.f, 0.f, 0.f, 0.f);
    __syncthreads();
    int b = blockIdx.x;
    int ecnt = cnts[b];
    size_t r0 = (size_t)b * CAPE;
    const uint4* rq = (const uint4*)(rec2 + r0);
    int nq = ecnt >> 2;
    for (int q = tid; q < nq; q += blockDim.x) {
        uint4 r = rq[q];
        float4 s0 = summary[r.x & SRCM];
        float4 s1 = summary[r.y & SRCM];
        float4 s2 = summary[r.z & SRCM];
        float4 s3 = summary[r.w & SRCM];
        float* p0 = &AB[(((r.x >> 26)) * NBIN + __float_as_uint(s0.z)) * 2];
        atomicAdd(p0, s0.x); atomicAdd(p0 + 1, s0.y);
        float* p1 = &AB[(((r.y >> 26)) * NBIN + __float_as_uint(s1.z)) * 2];
        atomicAdd(p1, s1.x); atomicAdd(p1 + 1, s1.y);
        float* p2 = &AB[(((r.z >> 26)) * NBIN + __float_as_uint(s2.z)) * 2];
        atomicAdd(p2, s2.x); atomicAdd(p2 + 1, s2.y);
        float* p3 = &AB[(((r.w >> 26)) * NBIN + __float_as_uint(s3.z)) * 2];
        atomicAdd(p3, s3.x); atomicAdd(p3 + 1, s3.y);
    }
    int e = (nq << 2) + tid;
    if (e < ecnt) {
        unsigned r = rec2[r0 + e];
        float4 sm = summary[r & SRCM];
        float* pp = &AB[((r >> 26) * NBIN + __float_as_uint(sm.z)) * 2];
        atomicAdd(pp, sm.x); atomicAdd(pp + 1, sm.y);
    }
    __syncthreads();
    int U = UcntS;
    int d = tid & 63;
    int w = tid >> 6;   // 0..3, wave w owns nodes [w*16, w*16+16)
    int n0b = w << 4;
    float2 abr[16];
#pragma unroll
    for (int j = 0; j < 16; ++j)
        abr[j] = *(const float2*)&AB[((n0b + j) * NBIN + d) * 2];
    float accv[16];
#pragma unroll
    for (int j = 0; j < 16; ++j) accv[j] = 0.f;
    for (int uu = 0; uu < U; ++uu) {
        int u = ulist[uu];  // wave-uniform
        float2 pq = PQ[u * DH + d];
        if (u < 64) {
#pragma unroll
            for (int j = 0; j < 16; ++j) {
                float ax = __int_as_float(__builtin_amdgcn_readlane(__float_as_int(abr[j].x), u));
                float ay = __int_as_float(__builtin_amdgcn_readlane(__float_as_int(abr[j].y), u));
                accv[j] += ax * pq.x + ay * pq.y;
            }
        } else {
#pragma unroll
            for (int j = 0; j < 16; ++j) {
                float2 v = *(const float2*)&AB[((n0b + j) * NBIN + 64) * 2];
                accv[j] += v.x * pq.x + v.y * pq.y;
            }
        }
    }
    // finish: self term + relu + sorted-batch strip pooling (sharded flush)
    float* psum = psum_s + (size_t)(b & (NSH - 1)) * G * DH;
    float* cnt  = cnt_s  + (size_t)(b & (NSH - 1)) * G;
    int n0 = b * BW;
    float bias = b2[d];
    float lsum = 0.f, lcnt = 0.f;
    int cb = -1;
    for (int j = 0; j < 16; ++j) {
        int i = n0 + n0b + j;
        if (i >= N) break;
        float4 sm = summary[i];
        int rb = (int)__float_as_uint(sm.z);
        float2 pq = PQ[rb * DH + d];
        float g = sm.x * pq.x + sm.y * pq.y;
        float v = fmaxf(sm.y * (accv[j] + g) + bias, 0.f);
        int bt = batch[i];
        if (bt != cb) {
            if (cb >= 0) {
                atomicAdd(&psum[cb * DH + d], lsum);
                if (d == 0) atomicAdd(&cnt[cb], lcnt);
            }
            cb = bt; lsum = 0.f; lcnt = 0.f;
        }
        lsum += v;
        if (d == 0) lcnt += 1.f;
    }
    if (cb >= 0) {
        atomicAdd(&psum[cb * DH + d], lsum);
        if (d == 0) atomicAdd(&cnt[cb], lcnt);
    }
}

// ---- out: one block per graph; reduce NSH shards, mean-pool, FC ----
__global__ __launch_bounds__(64) void k_out(const float* __restrict__ psum_s,
        const float* __restrict__ cnt_s, const float* __restrict__ fcW,
        const float* __restrict__ fcb, float* __restrict__ out, int G) {
    __shared__ float pooled[DH];
    int g = blockIdx.x, d = threadIdx.x;  // 64 threads
    float s = 0.f, cc = 0.f;
#pragma unroll
    for (int k = 0; k < NSH; ++k) {
        s += psum_s[(size_t)k * G * DH + g * DH + d];
        cc += cnt_s[(size_t)k * G + g];
    }
    pooled[d] = s / fmaxf(cc, 1.0f);
    __syncthreads();
    if (d < DOUT) {
        float o = 0.f;
#pragma unroll
        for (int kk = 0; kk < DH; ++kk) o += pooled[kk] * fcW[kk * DOUT + d];
        out[g * DOUT + d] = o + fcb[d];
    }
}

static inline size_t pad256(size_t n) { return (n + 255) & ~(size_t)255; }

extern "C" void kernel_launch(void* const* d_in, const int* in_sizes, int n_in,
                              void* d_out, int out_size, void* d_ws, size_t ws_size,
                              hipStream_t stream) {
    const int N = in_sizes[0];
    const int E = in_sizes[1] / 2;
    const int G = out_size / DOUT;
    const int NB = (N + BW - 1) / BW;
    const int chunk = (E + GPB - 1) / GPB;  // ~12500, fits u16

    const int* edge = (const int*)d_in[1];
    const int* src = edge;
    const int* dst = edge + E;
    const int* batch = (const int*)d_in[2];
    const float* emb = (const float*)d_in[3];
    const float* W1 = (const float*)d_in[4];
    const float* b1 = (const float*)d_in[5];
    const float* W2 = (const float*)d_in[6];
    const float* b2 = (const float*)d_in[7];
    const float* fcW = (const float*)d_in[8];
    const float* fcb = (const float*)d_in[9];
    float* out = (float*)d_out;

    // workspace. Zero region first: psum_s, cnt_s, flags (~135 KB).
    char* ws = (char*)d_ws;
    size_t off = 0;
    float* psum_s = (float*)(ws + off); off += pad256((size_t)NSH * G * DH) * 4;
    float* cnt_s  = (float*)(ws + off); off += pad256((size_t)NSH * G) * 4;
    int* flags  = (int*)(ws + off);    off += pad256(NBIN) * 4;
    size_t zero_bytes = off;
    unsigned* rec  = (unsigned*)(ws + off); off += pad256((size_t)GPB * chunk) * 4;   // ~6.4 MB
    unsigned* rec2 = (unsigned*)(ws + off); off += pad256((size_t)MAXNB * CAPE) * 4;  // 10.5 MB
    unsigned short* idx = (unsigned short*)(ws + off);
    off += pad256((size_t)GPB * (MAXNB + 1)) * 2;                                     // ~525 KB
    int* cnts    = (int*)(ws + off);    off += pad256(MAXNB) * 4;
    float* dinv  = (float*)(ws + off);  off += pad256(N) * 4;
    float* tarr  = (float*)(ws + off);  off += pad256(DH) * 4;
    float2* PQ   = (float2*)(ws + off); off += pad256(NBIN * DH) * 8;
    float4* summary = (float4*)(ws + off); off += pad256(N) * 16;
    // total ~ 20 MB

    hipMemsetAsync(d_ws, 0, zero_bytes, stream);

    const int B = 256;
    k_group<<<GPB + NBIN, 1024, 0, stream>>>(src, dst, rec, idx, emb, W1, b1, W2,
                                             tarr, PQ, E, NB, chunk);
    k_passA<<<NB, B, 0, stream>>>(idx, rec, rec2, cnts, dinv, N, chunk);
    k_passB<<<NB, B, 0, stream>>>(cnts, rec2, dinv, tarr, summary, flags, N);
    k_passC<<<NB, B, 0, stream>>>(cnts, rec2, summary, PQ, flags, b2, batch,
                                  psum_s, cnt_s, N, G);
    k_out<<<G, 64, 0, stream>>>(psum_s, cnt_s, fcW, fcb, out, G);
}

// Round 3
// 161.688 us; speedup vs baseline: 1.1942x; 1.0337x over previous
//
#include <hip/hip_runtime.h>
#include <hip/hip_bf16.h>

// GCN fused pipeline for MI355X — block-local counting sort (NO global atomics,
// NO scattered global writes), binary-search output-major merge, LDS-local
// E-passes, 8-way sharded pooling atomics.
// vocab=1 => h1[i] = relu(embW1*c_i + b1) piecewise-linear in scalar c_i with
// <=65 ReLU patterns (bins). g[i] = a_i*P[bin_i] + b_i*Q[bin_i].
// agg_i[d] = sum_u A_i[u]*P[u][d] + B_i[u]*Q[u][d], (A,B) per-(node,bin) LDS
// sums (2 LDS atomics/edge).
// Lessons: R6 - no E-scale global atomics (64B line write-through each);
// R11 - no cooperative grid.sync (8 XCDs); R12 - contended global atomic
// flush is a 71us-class floor -> shard psum/cnt; R13 - raising k_group blocks
// with global cursor atomics quadruples atomic write-through (WRITE 26->60MB);
// R14 - 512-thread passC regressed (VGPR cap) -> keep 256-thr passC; counting
// sort front half landed at ~60us: passA's 2-threads-per-run gather makes a
// wave touch 64 scattered 24B runs (4B useful/64B line) with no ILP.
// R15 (this round): passA rewritten as OUTPUT-major merge — each thread owns
// consecutive merged slots o, binary-searches the LDS run-prefix (7 steps) for
// its source run. Wave reads ~10 adjacent runs (5x fewer line txns), rec2
// stores perfectly coalesced, 3 independent iters/thread for ILP.
// Inputs: 0 x[int32 N], 1 edge_index[int32 2*E] (src then dst), 2 batch[int32 N sorted],
// 3 emb[1*64], 4 W1[64*64], 5 b1[64], 6 W2[64*64], 7 b2[64], 8 fcW[64*32], 9 fcb[32].
// Output: [G=64, 32] fp32.

#define DH 64
#define DOUT 32
#define NBIN 65
#define BW 64          // bucket width (nodes per bucket)
#define MAXNB 2048     // max buckets (N <= 131072)
#define SCAN_N 2048    // scan width (>= NB, pow2)
#define SRCM 0x3FFFFFF // 26-bit src mask (N < 2^26)
#define CAPE 1280      // per-bucket compacted capacity (16B-aligned: 1280*4=5120)
#define GPB 128        // group blocks; chunk = E/GPB ~ 12500 (fits u16 idx)
#define NSH 8          // pooling shards

// ---- group: per-block LDS counting sort -> block-private dense region + u16
// run index. Extra NBIN blocks compute PQ tables. ----
__global__ __launch_bounds__(1024) void k_group(
        const int* __restrict__ src, const int* __restrict__ dst,
        unsigned* __restrict__ rec, unsigned short* __restrict__ idx,
        const float* __restrict__ emb, const float* __restrict__ W1,
        const float* __restrict__ b1, const float* __restrict__ W2,
        float* __restrict__ tarr, float2* __restrict__ PQ, int E, int NB, int chunk) {
    __shared__ int lh[SCAN_N];
    __shared__ int lb[SCAN_N];
    __shared__ float ewl[DH], tl[DH], bl[DH];
    __shared__ int rl[DH], sl[DH];
    int tid = threadIdx.x, bid = blockIdx.x;
    if (bid >= GPB) {
        // ---- tables part: beta = bid-GPB in 0..64, 64 working threads ----
        int beta = bid - GPB;
        int k = tid;
        float s = 0.f, t = 0.f;
        if (k < DH) {
#pragma unroll
            for (int j = 0; j < DH; ++j) s += emb[j] * W1[j * DH + k];
            t = (s != 0.f) ? (-b1[k] / s) : INFINITY;
            ewl[k] = s; tl[k] = t; bl[k] = b1[k];
        }
        __syncthreads();
        if (k < DH) {
            int r = 0, ss = 0;
#pragma unroll
            for (int j = 0; j < DH; ++j) { r += (tl[j] <= t); ss += (tl[j] < t); }
            rl[k] = r; sl[k] = ss;
            if (beta == 0) tarr[k] = t;
        }
        __syncthreads();
        if (k < DH) {
            float p = 0.f, q = 0.f;
            for (int kk = 0; kk < DH; ++kk) {
                float e = ewl[kk];
                bool act;
                if (e > 0.f) act = (beta >= rl[kk]);
                else if (e < 0.f) act = (beta <= sl[kk]);
                else act = (bl[kk] > 0.f);
                if (act) {
                    float w = W2[kk * DH + k];
                    p += e * w;
                    q += bl[kk] * w;
                }
            }
            PQ[beta * DH + k] = make_float2(p, q);
        }
        return;
    }
    // ---- group part: local counting sort of chunk [c0,c1) ----
    int c0 = bid * chunk;
    int c1 = min(c0 + chunk, E);
    for (int t = tid; t < SCAN_N; t += 1024) lh[t] = 0;
    __syncthreads();
    for (int e = c0 + tid; e < c1; e += 1024)
        atomicAdd(&lh[dst[e] >> 6], 1);
    __syncthreads();
    for (int t = tid; t < SCAN_N; t += 1024) lb[t] = lh[t];
    __syncthreads();
    // inclusive scan of lb over SCAN_N (Hillis-Steele, 2 elems/thread)
    for (int ofs = 1; ofs < SCAN_N; ofs <<= 1) {
        int i1 = tid + 1024;
        int v0 = (tid >= ofs) ? lb[tid - ofs] : 0;
        int v1 = (i1 >= ofs) ? lb[i1 - ofs] : 0;
        __syncthreads();
        lb[tid] += v0; lb[i1] += v1;
        __syncthreads();
    }
    // exclusive base = incl - count; emit u16 index; keep base in lb
    size_t ib = (size_t)bid * (MAXNB + 1);
    for (int t = tid; t < NB; t += 1024) {
        int base = lb[t] - lh[t];
        idx[ib + t] = (unsigned short)base;
        lb[t] = base;
    }
    if (tid == 0) idx[ib + NB] = (unsigned short)(c1 - c0);
    __syncthreads();
    for (int t = tid; t < NB; t += 1024) lh[t] = 0;
    __syncthreads();
    // scatter into block-private dense region (writes stay within 50KB,
    // single-XCD, dense writeback; no cross-block line sharing)
    for (int e = c0 + tid; e < c1; e += 1024) {
        int s = src[e], dd = dst[e];
        int bk = dd >> 6;
        int o = lb[bk] + atomicAdd(&lh[bk], 1);
        rec[(size_t)bid * chunk + o] = (unsigned)s | ((unsigned)(dd & 63) << 26);
    }
}

// ---- pass A: OUTPUT-major merge of GPB runs per bucket. Each thread owns
// consecutive merged slots o and binary-searches the LDS run-prefix for its
// source run: wave reads ~10 adjacent runs (vs 64 scattered), rec2 stores
// coalesced. Also counts deg -> dinv. ----
__global__ __launch_bounds__(256) void k_passA(const unsigned short* __restrict__ idx,
        const unsigned* __restrict__ rec, unsigned* __restrict__ rec2,
        int* __restrict__ cnts, float* __restrict__ dinv, int N, int chunk) {
    __shared__ int rst[GPB];   // run start (global rec index)
    __shared__ int ps[GPB];    // inclusive prefix of run lengths
    __shared__ int cl[BW];
    int tid = threadIdx.x, bk = blockIdx.x;
    if (tid < BW) cl[tid] = 0;
    if (tid < GPB) {
        size_t ib = (size_t)tid * (MAXNB + 1);
        int s = idx[ib + bk];
        int e = idx[ib + bk + 1];
        rst[tid] = tid * chunk + s;
        ps[tid] = e - s;
    }
    __syncthreads();
    // inclusive scan of run lengths over GPB (128)
    for (int ofs = 1; ofs < GPB; ofs <<= 1) {
        int v = (tid < GPB && tid >= ofs) ? ps[tid - ofs] : 0;
        __syncthreads();
        if (tid < GPB) ps[tid] += v;
        __syncthreads();
    }
    int T = ps[GPB - 1];
    if (tid == 0) cnts[bk] = min(T, CAPE);
    size_t r2 = (size_t)bk * CAPE;
    for (int o = tid; o < T; o += 256) {
        // r = smallest index with ps[r] > o  (7-step binary search)
        int r = 0;
#pragma unroll
        for (int s = 64; s > 0; s >>= 1)
            if (r + s <= GPB && ps[r + s - 1] <= o) r += s;
        int base = (r > 0) ? ps[r - 1] : 0;
        unsigned v = rec[rst[r] + (o - base)];
        atomicAdd(&cl[v >> 26], 1);
        if (o < CAPE) rec2[r2 + o] = v;
    }
    __syncthreads();
    if (tid < BW) {
        int i = bk * BW + tid;
        if (i < N) dinv[i] = rsqrtf((float)cl[tid] + 1.0f);
    }
}

// ---- pass B: per-bucket S (uint4 rec2 loads, LDS atomics) -> summary4, flags ----
__global__ __launch_bounds__(256, 8) void k_passB(const int* __restrict__ cnts,
        const unsigned* __restrict__ rec2, const float* __restrict__ dinv,
        const float* __restrict__ tarr, float4* __restrict__ summary,
        int* __restrict__ flags, int N) {
    __shared__ float Sl[BW];
    __shared__ float tl[DH];
    int tid = threadIdx.x;
    if (tid < BW) Sl[tid] = 0.f;
    if (tid < DH) tl[tid] = tarr[tid];
    __syncthreads();
    int b = blockIdx.x;
    int cnt = cnts[b];
    size_t r0 = (size_t)b * CAPE;
    const uint4* rq = (const uint4*)(rec2 + r0);  // r0*4 = b*5120, 16B aligned
    int nq = cnt >> 2;
    for (int q = tid; q < nq; q += blockDim.x) {
        uint4 r = rq[q];
        float d0 = dinv[r.x & SRCM];
        float d1 = dinv[r.y & SRCM];
        float d2 = dinv[r.z & SRCM];
        float d3 = dinv[r.w & SRCM];
        atomicAdd(&Sl[r.x >> 26], d0);
        atomicAdd(&Sl[r.y >> 26], d1);
        atomicAdd(&Sl[r.z >> 26], d2);
        atomicAdd(&Sl[r.w >> 26], d3);
    }
    int e = (nq << 2) + tid;
    if (e < cnt) {
        unsigned r = rec2[r0 + e];
        atomicAdd(&Sl[r >> 26], dinv[r & SRCM]);
    }
    __syncthreads();
    if (tid < BW) {
        int i = b * BW + tid;
        if (i < N) {
            float di = dinv[i];
            float c = di * (Sl[tid] + di);
            int bb = 0;
#pragma unroll
            for (int j = 0; j < DH; ++j) bb += (tl[j] < c);
            summary[i] = make_float4(di * c, di, __uint_as_float((unsigned)bb), 0.f);
            flags[bb] = 1;  // benign race: same value
        }
    }
}

// ---- pass C: AB accumulate (uint4 rec2, 2 LDS atomics/edge), compact ulist +
// readlane U-dot, self term + relu + SHARDED sorted-batch strip pooling.
// (round-0 known-good 256-thread version) ----
__global__ __launch_bounds__(256, 4) void k_passC(const int* __restrict__ cnts,
        const unsigned* __restrict__ rec2, const float4* __restrict__ summary,
        const float2* __restrict__ PQ, const int* __restrict__ flags,
        const float* __restrict__ b2, const int* __restrict__ batch,
        float* __restrict__ psum_s, float* __restrict__ cnt_s, int N, int G) {
    __shared__ __align__(16) float AB[BW * NBIN * 2];  // 33,280 B
    __shared__ unsigned char ulist[NBIN + 3];
    __shared__ int UcntS;
    int tid = threadIdx.x;  // 256
    // used-bin list via ballot
    if (tid < 64) {
        int act = (flags[tid] != 0);
        unsigned long long m = __ballot(act);
        int pos = __popcll(m & ((1ull << tid) - 1ull));
        if (act) ulist[pos] = (unsigned char)tid;
        if (tid == 0) {
            int total = __popcll(m);
            if (flags[64]) ulist[total++] = 64;
            UcntS = total;
        }
    }
    // zero AB float4-wide (8320 floats = 2080 float4)
    float4* AB4 = (float4*)AB;
    for (int t = tid; t < (BW * NBIN * 2) / 4; t += blockDim.x)
        AB4[t] = make_float4(0.f, 0.f, 0.f, 0.f);
    __syncthreads();
    int b = blockIdx.x;
    int ecnt = cnts[b];
    size_t r0 = (size_t)b * CAPE;
    const uint4* rq = (const uint4*)(rec2 + r0);
    int nq = ecnt >> 2;
    for (int q = tid; q < nq; q += blockDim.x) {
        uint4 r = rq[q];
        float4 s0 = summary[r.x & SRCM];
        float4 s1 = summary[r.y & SRCM];
        float4 s2 = summary[r.z & SRCM];
        float4 s3 = summary[r.w & SRCM];
        float* p0 = &AB[(((r.x >> 26)) * NBIN + __float_as_uint(s0.z)) * 2];
        atomicAdd(p0, s0.x); atomicAdd(p0 + 1, s0.y);
        float* p1 = &AB[(((r.y >> 26)) * NBIN + __float_as_uint(s1.z)) * 2];
        atomicAdd(p1, s1.x); atomicAdd(p1 + 1, s1.y);
        float* p2 = &AB[(((r.z >> 26)) * NBIN + __float_as_uint(s2.z)) * 2];
        atomicAdd(p2, s2.x); atomicAdd(p2 + 1, s2.y);
        float* p3 = &AB[(((r.w >> 26)) * NBIN + __float_as_uint(s3.z)) * 2];
        atomicAdd(p3, s3.x); atomicAdd(p3 + 1, s3.y);
    }
    int e = (nq << 2) + tid;
    if (e < ecnt) {
        unsigned r = rec2[r0 + e];
        float4 sm = summary[r & SRCM];
        float* pp = &AB[((r >> 26) * NBIN + __float_as_uint(sm.z)) * 2];
        atomicAdd(pp, sm.x); atomicAdd(pp + 1, sm.y);
    }
    __syncthreads();
    int U = UcntS;
    int d = tid & 63;
    int w = tid >> 6;   // 0..3, wave w owns nodes [w*16, w*16+16)
    int n0b = w << 4;
    float2 abr[16];
#pragma unroll
    for (int j = 0; j < 16; ++j)
        abr[j] = *(const float2*)&AB[((n0b + j) * NBIN + d) * 2];
    float accv[16];
#pragma unroll
    for (int j = 0; j < 16; ++j) accv[j] = 0.f;
    for (int uu = 0; uu < U; ++uu) {
        int u = ulist[uu];  // wave-uniform
        float2 pq = PQ[u * DH + d];
        if (u < 64) {
#pragma unroll
            for (int j = 0; j < 16; ++j) {
                float ax = __int_as_float(__builtin_amdgcn_readlane(__float_as_int(abr[j].x), u));
                float ay = __int_as_float(__builtin_amdgcn_readlane(__float_as_int(abr[j].y), u));
                accv[j] += ax * pq.x + ay * pq.y;
            }
        } else {
#pragma unroll
            for (int j = 0; j < 16; ++j) {
                float2 v = *(const float2*)&AB[((n0b + j) * NBIN + 64) * 2];
                accv[j] += v.x * pq.x + v.y * pq.y;
            }
        }
    }
    // finish: self term + relu + sorted-batch strip pooling (sharded flush)
    float* psum = psum_s + (size_t)(b & (NSH - 1)) * G * DH;
    float* cnt  = cnt_s  + (size_t)(b & (NSH - 1)) * G;
    int n0 = b * BW;
    float bias = b2[d];
    float lsum = 0.f, lcnt = 0.f;
    int cb = -1;
    for (int j = 0; j < 16; ++j) {
        int i = n0 + n0b + j;
        if (i >= N) break;
        float4 sm = summary[i];
        int rb = (int)__float_as_uint(sm.z);
        float2 pq = PQ[rb * DH + d];
        float g = sm.x * pq.x + sm.y * pq.y;
        float v = fmaxf(sm.y * (accv[j] + g) + bias, 0.f);
        int bt = batch[i];
        if (bt != cb) {
            if (cb >= 0) {
                atomicAdd(&psum[cb * DH + d], lsum);
                if (d == 0) atomicAdd(&cnt[cb], lcnt);
            }
            cb = bt; lsum = 0.f; lcnt = 0.f;
        }
        lsum += v;
        if (d == 0) lcnt += 1.f;
    }
    if (cb >= 0) {
        atomicAdd(&psum[cb * DH + d], lsum);
        if (d == 0) atomicAdd(&cnt[cb], lcnt);
    }
}

// ---- out: one block per graph; reduce NSH shards, mean-pool, FC ----
__global__ __launch_bounds__(64) void k_out(const float* __restrict__ psum_s,
        const float* __restrict__ cnt_s, const float* __restrict__ fcW,
        const float* __restrict__ fcb, float* __restrict__ out, int G) {
    __shared__ float pooled[DH];
    int g = blockIdx.x, d = threadIdx.x;  // 64 threads
    float s = 0.f, cc = 0.f;
#pragma unroll
    for (int k = 0; k < NSH; ++k) {
        s += psum_s[(size_t)k * G * DH + g * DH + d];
        cc += cnt_s[(size_t)k * G + g];
    }
    pooled[d] = s / fmaxf(cc, 1.0f);
    __syncthreads();
    if (d < DOUT) {
        float o = 0.f;
#pragma unroll
        for (int kk = 0; kk < DH; ++kk) o += pooled[kk] * fcW[kk * DOUT + d];
        out[g * DOUT + d] = o + fcb[d];
    }
}

static inline size_t pad256(size_t n) { return (n + 255) & ~(size_t)255; }

extern "C" void kernel_launch(void* const* d_in, const int* in_sizes, int n_in,
                              void* d_out, int out_size, void* d_ws, size_t ws_size,
                              hipStream_t stream) {
    const int N = in_sizes[0];
    const int E = in_sizes[1] / 2;
    const int G = out_size / DOUT;
    const int NB = (N + BW - 1) / BW;
    const int chunk = (E + GPB - 1) / GPB;  // ~12500, fits u16

    const int* edge = (const int*)d_in[1];
    const int* src = edge;
    const int* dst = edge + E;
    const int* batch = (const int*)d_in[2];
    const float* emb = (const float*)d_in[3];
    const float* W1 = (const float*)d_in[4];
    const float* b1 = (const float*)d_in[5];
    const float* W2 = (const float*)d_in[6];
    const float* b2 = (const float*)d_in[7];
    const float* fcW = (const float*)d_in[8];
    const float* fcb = (const float*)d_in[9];
    float* out = (float*)d_out;

    // workspace. Zero region first: psum_s, cnt_s, flags (~135 KB).
    char* ws = (char*)d_ws;
    size_t off = 0;
    float* psum_s = (float*)(ws + off); off += pad256((size_t)NSH * G * DH) * 4;
    float* cnt_s  = (float*)(ws + off); off += pad256((size_t)NSH * G) * 4;
    int* flags  = (int*)(ws + off);    off += pad256(NBIN) * 4;
    size_t zero_bytes = off;
    unsigned* rec  = (unsigned*)(ws + off); off += pad256((size_t)GPB * chunk) * 4;   // ~6.4 MB
    unsigned* rec2 = (unsigned*)(ws + off); off += pad256((size_t)MAXNB * CAPE) * 4;  // 10.5 MB
    unsigned short* idx = (unsigned short*)(ws + off);
    off += pad256((size_t)GPB * (MAXNB + 1)) * 2;                                     // ~525 KB
    int* cnts    = (int*)(ws + off);    off += pad256(MAXNB) * 4;
    float* dinv  = (float*)(ws + off);  off += pad256(N) * 4;
    float* tarr  = (float*)(ws + off);  off += pad256(DH) * 4;
    float2* PQ   = (float2*)(ws + off); off += pad256(NBIN * DH) * 8;
    float4* summary = (float4*)(ws + off); off += pad256(N) * 16;
    // total ~ 20 MB

    hipMemsetAsync(d_ws, 0, zero_bytes, stream);

    const int B = 256;
    k_group<<<GPB + NBIN, 1024, 0, stream>>>(src, dst, rec, idx, emb, W1, b1, W2,
                                             tarr, PQ, E, NB, chunk);
    k_passA<<<NB, B, 0, stream>>>(idx, rec, rec2, cnts, dinv, N, chunk);
    k_passB<<<NB, B, 0, stream>>>(cnts, rec2, dinv, tarr, summary, flags, N);
    k_passC<<<NB, B, 0, stream>>>(cnts, rec2, summary, PQ, flags, b2, batch,
                                  psum_s, cnt_s, N, G);
    k_out<<<G, 64, 0, stream>>>(psum_s, cnt_s, fcW, fcb, out, G);
}